// Round 4
// baseline (417.094 us; speedup 1.0000x reference)
//
#include <hip/hip_runtime.h>

#define B 32
#define LC 512
#define LQ 64
#define DD 1024

// ws layout (floats):
// mfull  [B*LC]          @ 0        (16384)
// s0g    [B*LC]          @ 16384    (16384)   -> 32768
// q2c    [B*DD]          @ 32768    (32768)   -> 65536
// s1part [B*16*64]       @ 65536    (32768)   -> 98304
// P      [B*LC*LQ] bf16  @ 98304    (524288)  -> 622592
// qbf    [B*LQ*DD] bf16  @ 622592   (1048576) -> 1671168
// qT     [B*DD*LQ] bf16  @ 1671168  (1048576) -> 2719744
// Abf    [B*LC*DD] bf16  @ 2719744  (8388608) -> 11108352  (~44.4 MB)

typedef __attribute__((ext_vector_type(8))) short bf16x8;   // 8 bf16 (4 VGPRs)
typedef __attribute__((ext_vector_type(4))) float f32x4;    // MFMA C/D

__device__ inline short f2bf(float f) {
    unsigned u = __builtin_bit_cast(unsigned, f);
    u += 0x7FFFu + ((u >> 16) & 1u);   // RNE
    return (short)(u >> 16);
}

__device__ inline bf16x8 pack8(float4 a, float4 b) {
    bf16x8 r;
    r[0] = f2bf(a.x); r[1] = f2bf(a.y); r[2] = f2bf(a.z); r[3] = f2bf(a.w);
    r[4] = f2bf(b.x); r[5] = f2bf(b.y); r[6] = f2bf(b.z); r[7] = f2bf(b.w);
    return r;
}

__device__ inline float dot4(float4 a, float4 b) {
    return a.x * b.x + a.y * b.y + a.z * b.z + a.w * b.w;
}

// XCD-aware bijective swizzle (nwg % 8 == 0): each XCD gets a contiguous chunk.
__device__ inline int xswz(int bid, int nwg) {
    return (bid & 7) * (nwg >> 3) + (bid >> 3);
}

// 4x4 transpose among lanes within quartets (shfl xor 1, xor 2).
__device__ inline void xpose44(float v[4], int l15) {
    const bool m0 = l15 & 1, m1 = l15 & 2;
    float x0 = m0 ? v[0] : v[1];
    float x1 = m0 ? v[2] : v[3];
    x0 = __shfl_xor(x0, 1, 64);
    x1 = __shfl_xor(x1, 1, 64);
    if (m0) { v[0] = x0; v[2] = x1; } else { v[1] = x0; v[3] = x1; }
    float y0 = m1 ? v[0] : v[2];
    float y1 = m1 ? v[1] : v[3];
    y0 = __shfl_xor(y0, 2, 64);
    y1 = __shfl_xor(y1, 2, 64);
    if (m1) { v[0] = y0; v[1] = y1; } else { v[2] = y0; v[3] = y1; }
}

// ---------------- kernel prep: fused c-prep + q-prep (1024 blocks) ----------------
// blocks 0..511: Abf = bf16(c * proj_cq), s0 = c . proj_c     (streams c once)
// blocks 512..1023: qbf = bf16(q), qT = bf16(q)^T, s1 partials (streams q once)
__global__ __launch_bounds__(256) void kprep(const float* __restrict__ c,
                                             const float* __restrict__ q,
                                             const float* __restrict__ proj_c,
                                             const float* __restrict__ proj_q,
                                             const float* __restrict__ proj_cq,
                                             short* __restrict__ Abf,
                                             float* __restrict__ s0g,
                                             short* __restrict__ qbf,
                                             short* __restrict__ qT,
                                             float* __restrict__ s1part) {
    const int half = blockIdx.x >> 9;
    const int bid  = xswz(blockIdx.x & 511, 512);
    const int t    = threadIdx.x;

    if (half == 0) {
        // ---- c-prep: block = (b, 32-row tile) ----
        const int b  = bid >> 4;
        const int i0 = (bid & 15) * 32;
        const int arow = t >> 3, ag = t & 7;
        __shared__ float s0red[32][8];

        const float* cb = c + (size_t)(b * LC + i0 + arow) * DD + ag * 8;
        short* ab = Abf + (size_t)(b * LC + i0 + arow) * DD + ag * 8;
        float s0p = 0.f;
#pragma unroll 4
        for (int kc = 0; kc < 16; ++kc) {
            float4 a0 = *(const float4*)(cb + kc * 64);
            float4 a1 = *(const float4*)(cb + kc * 64 + 4);
            float4 p0 = *(const float4*)(proj_cq + kc * 64 + ag * 8);
            float4 p1 = *(const float4*)(proj_cq + kc * 64 + ag * 8 + 4);
            float4 c0 = *(const float4*)(proj_c + kc * 64 + ag * 8);
            float4 c1 = *(const float4*)(proj_c + kc * 64 + ag * 8 + 4);
            s0p += dot4(a0, c0) + dot4(a1, c1);
            float4 m0 = {a0.x * p0.x, a0.y * p0.y, a0.z * p0.z, a0.w * p0.w};
            float4 m1 = {a1.x * p1.x, a1.y * p1.y, a1.z * p1.z, a1.w * p1.w};
            *(bf16x8*)(ab + kc * 64) = pack8(m0, m1);
        }
        s0red[arow][ag] = s0p;
        __syncthreads();
        if (t < 32) {
            float s = 0.f;
#pragma unroll
            for (int k = 0; k < 8; ++k) s += s0red[t][k];
            s0g[b * LC + i0 + t] = s;
        }
    } else {
        // ---- q-prep: block = (b, 64-d slice) ----
        const int b  = bid >> 4;
        const int d0 = (bid & 15) * 64;
        const int sl = bid & 15;
        __shared__ __align__(16) short tile[64][72];   // [local d][j]
        __shared__ float s1red[64][8];

        const int j0 = (t & 31) * 2;   // rows j0, j0+1
        const int dg = t >> 5;         // d-offset dg*8

        const float* qr0 = q + (size_t)(b * LQ + j0) * DD + d0 + dg * 8;
        const float* qr1 = qr0 + DD;
        float4 x0 = *(const float4*)(qr0 + 0);
        float4 x1 = *(const float4*)(qr0 + 4);
        float4 y0 = *(const float4*)(qr1 + 0);
        float4 y1 = *(const float4*)(qr1 + 4);
        float4 p0 = *(const float4*)(proj_q + d0 + dg * 8);
        float4 p1 = *(const float4*)(proj_q + d0 + dg * 8 + 4);

        s1red[j0][dg]     = dot4(x0, p0) + dot4(x1, p1);
        s1red[j0 + 1][dg] = dot4(y0, p0) + dot4(y1, p1);

        *(bf16x8*)&qbf[(size_t)(b * LQ + j0) * DD + d0 + dg * 8]     = pack8(x0, x1);
        *(bf16x8*)&qbf[(size_t)(b * LQ + j0 + 1) * DD + d0 + dg * 8] = pack8(y0, y1);

        const float* fx0 = (const float*)&x0;
        const float* fx1 = (const float*)&x1;
        const float* fy0 = (const float*)&y0;
        const float* fy1 = (const float*)&y1;
#pragma unroll
        for (int e = 0; e < 8; ++e) {
            float v0 = (e < 4) ? fx0[e] : fx1[e - 4];
            float v1 = (e < 4) ? fy0[e] : fy1[e - 4];
            unsigned pk = (unsigned)(unsigned short)f2bf(v0)
                        | ((unsigned)(unsigned short)f2bf(v1) << 16);
            *(unsigned*)&tile[dg * 8 + e][j0] = pk;
        }
        __syncthreads();

        {
            const int d = t >> 2, part = t & 3;
            bf16x8 v0 = *(const bf16x8*)&tile[d][part * 16];
            bf16x8 v1 = *(const bf16x8*)&tile[d][part * 16 + 8];
            short* dst = qT + ((size_t)b * DD + d0 + d) * LQ + part * 16;
            *(bf16x8*)(dst)     = v0;
            *(bf16x8*)(dst + 8) = v1;
        }
        if (t < 64) {
            float s = 0.f;
#pragma unroll
            for (int k = 0; k < 8; ++k) s += s1red[t][k];
            s1part[(b * 16 + sl) * 64 + t] = s;
        }
    }
}

// ---------------- kernel 1: sim via bf16 MFMA from precomputed Abf ----------------
// 512 blocks, 256 threads = 4 waves. M=32 x N=64 tile. Whole 64-KB A-panel staged
// in LDS ONCE, one barrier, then 64 fully-unrolled MFMAs with zero loop barriers.
// B-frags stream from qbf (L2-hot). Epilogue: row softmax -> P bf16, mfull.
__global__ __launch_bounds__(256) void k1_sim(const short* __restrict__ Abf,
                                              const short* __restrict__ qbf,
                                              const float* __restrict__ s0g,
                                              const float* __restrict__ s1part,
                                              short* __restrict__ P,
                                              float* __restrict__ mfull) {
    const int bid = xswz(blockIdx.x, 512);
    const int b  = bid >> 4;
    const int i0 = (bid & 15) * 32;
    const int t  = threadIdx.x;
    const int w  = t >> 6, lane = t & 63;
    const int l15 = lane & 15, quad = lane >> 4;

    // row stride 1032 shorts: bank group = 4*((l15+quad)%8) -> uniform 8 banks x 8 lanes
    __shared__ __align__(16) short sA[32 * 1032];
    __shared__ float rmaxL[32][4];
    __shared__ float rsumL[32][4];
    __shared__ float s1L[64];

    const int arow = t >> 3, ag = t & 7;
    const short* asrc = Abf + (size_t)(b * LC + i0 + arow) * DD + ag * 8;
    short* adst = sA + arow * 1032 + ag * 8;

    // stage whole panel: 16 x 16B per thread
    bf16x8 stg[16];
#pragma unroll
    for (int kc = 0; kc < 16; ++kc) stg[kc] = *(const bf16x8*)(asrc + kc * 64);
#pragma unroll
    for (int kc = 0; kc < 16; ++kc) *(bf16x8*)(adst + kc * 64) = stg[kc];

    if (t < 64) {
        float s = 0.f;
#pragma unroll
        for (int k = 0; k < 16; ++k) s += s1part[(b * 16 + k) * 64 + t];
        s1L[t] = s;
    }
    __syncthreads();   // the only pre-epilogue barrier

    const short* qfrag = qbf + (size_t)(b * LQ + w * 16 + l15) * DD + quad * 8;
    f32x4 acc[2] = {{0.f,0.f,0.f,0.f},{0.f,0.f,0.f,0.f}};

#pragma unroll
    for (int kc = 0; kc < 16; ++kc) {
        bf16x8 bq0 = *(const bf16x8*)(qfrag + kc * 64);
        bf16x8 bq1 = *(const bf16x8*)(qfrag + kc * 64 + 32);
#pragma unroll
        for (int mt = 0; mt < 2; ++mt) {
            bf16x8 af = *(const bf16x8*)(sA + (mt * 16 + l15) * 1032 + kc * 64 + quad * 8);
            acc[mt] = __builtin_amdgcn_mfma_f32_16x16x32_bf16(af, bq0, acc[mt], 0, 0, 0);
        }
#pragma unroll
        for (int mt = 0; mt < 2; ++mt) {
            bf16x8 af = *(const bf16x8*)(sA + (mt * 16 + l15) * 1032 + kc * 64 + 32 + quad * 8);
            acc[mt] = __builtin_amdgcn_mfma_f32_16x16x32_bf16(af, bq1, acc[mt], 0, 0, 0);
        }
    }

    // ---- epilogue: row softmax, write P bf16 + mfull ----
    const float s1j = s1L[w * 16 + l15];
    float v[2][4];
#pragma unroll
    for (int mt = 0; mt < 2; ++mt) {
#pragma unroll
        for (int r = 0; r < 4; ++r) {
            float vv = acc[mt][r] + s1j;
            v[mt][r] = vv;
            float rm = vv;
#pragma unroll
            for (int off = 1; off < 16; off <<= 1) rm = fmaxf(rm, __shfl_xor(rm, off, 16));
            if (l15 == 0) rmaxL[mt * 16 + quad * 4 + r][w] = rm;
        }
    }
    __syncthreads();
    float e[2][4];
#pragma unroll
    for (int mt = 0; mt < 2; ++mt) {
#pragma unroll
        for (int r = 0; r < 4; ++r) {
            int row = mt * 16 + quad * 4 + r;
            float m = fmaxf(fmaxf(rmaxL[row][0], rmaxL[row][1]),
                            fmaxf(rmaxL[row][2], rmaxL[row][3]));
            float ee = __expf(v[mt][r] - m);
            e[mt][r] = ee;
            float se = ee;
#pragma unroll
            for (int off = 1; off < 16; off <<= 1) se += __shfl_xor(se, off, 16);
            if (l15 == 0) rsumL[row][w] = se;
        }
    }
    __syncthreads();
#pragma unroll
    for (int mt = 0; mt < 2; ++mt) {
#pragma unroll
        for (int r = 0; r < 4; ++r) {
            int row = mt * 16 + quad * 4 + r;
            float s = rsumL[row][0] + rsumL[row][1] + rsumL[row][2] + rsumL[row][3];
            P[(size_t)(b * LC + i0 + row) * LQ + w * 16 + l15] = f2bf(e[mt][r] / s);
        }
    }
    if (t < 32) {
        float mm = fmaxf(fmaxf(rmaxL[t][0], rmaxL[t][1]),
                         fmaxf(rmaxL[t][2], rmaxL[t][3]));
        mfull[b * LC + i0 + t] = mm + s0g[b * LC + i0 + t];
    }
}

// ---------------- kernel 2: fused softmax_i(mfull) + q2c[b,d] = sum_i a[i]*c[b,i,d] ----------------
__global__ __launch_bounds__(256) void k2_q2c(const float* __restrict__ c,
                                              const float* __restrict__ mfull,
                                              float* __restrict__ q2c) {
    const int bid = xswz(blockIdx.x, 256);
    const int b  = bid >> 3;
    const int d0 = (bid & 7) * 128;
    const int t  = threadIdx.x;
    __shared__ float aL[LC];
    __shared__ float redm[4];
    __shared__ float reds[4];

    float m0 = mfull[b * LC + t];
    float m1 = mfull[b * LC + 256 + t];
    float mx = fmaxf(m0, m1);
#pragma unroll
    for (int off = 32; off; off >>= 1) mx = fmaxf(mx, __shfl_xor(mx, off, 64));
    if ((t & 63) == 0) redm[t >> 6] = mx;
    __syncthreads();
    float bm = fmaxf(fmaxf(redm[0], redm[1]), fmaxf(redm[2], redm[3]));
    float e0 = __expf(m0 - bm), e1 = __expf(m1 - bm);
    float s = e0 + e1;
#pragma unroll
    for (int off = 32; off; off >>= 1) s += __shfl_xor(s, off, 64);
    if ((t & 63) == 0) reds[t >> 6] = s;
    __syncthreads();
    float bs = reds[0] + reds[1] + reds[2] + reds[3];
    float inv = 1.0f / bs;
    aL[t] = e0 * inv;
    aL[t + 256] = e1 * inv;
    __syncthreads();

    const int tx = t & 31, ty = t >> 5;
    float4 acc = {0.f, 0.f, 0.f, 0.f};
    const float* cb = c + (size_t)b * LC * DD + d0 + tx * 4;
    for (int i = ty; i < LC; i += 8) {
        float a = aL[i];
        float4 cv = *(const float4*)(cb + (size_t)i * DD);
        acc.x += a * cv.x; acc.y += a * cv.y; acc.z += a * cv.z; acc.w += a * cv.w;
    }
    __shared__ __align__(16) float4 red[8][32];
    red[ty][tx] = acc;
    __syncthreads();
    if (t < 32) {
        float4 sv = red[0][t];
#pragma unroll
        for (int k = 1; k < 8; ++k) {
            float4 v2 = red[k][t];
            sv.x += v2.x; sv.y += v2.y; sv.z += v2.z; sv.w += v2.w;
        }
        *(float4*)(q2c + b * DD + d0 + t * 4) = sv;
    }
}

// ---------------- kernel 3: LDS-free, barrier-free streaming c2q + concat write ----------------
__global__ __launch_bounds__(256) void k3_out(const float* __restrict__ c,
                                              const short* __restrict__ qT,
                                              const short* __restrict__ P,
                                              const float* __restrict__ q2c,
                                              float* __restrict__ out) {
    const int bid = xswz(blockIdx.x, 2048);
    const int b  = bid >> 6;
    const int i0 = ((bid >> 2) & 15) * 32;
    const int qd = bid & 3;                 // D-quarter: 256 d
    const int t  = threadIdx.x;
    const int w  = t >> 6, lane = t & 63;
    const int l15 = lane & 15, quad = lane >> 4;

    // P A-fragments: reg-resident, invariant over d
    bf16x8 paf[2][2];
#pragma unroll
    for (int s = 0; s < 2; ++s)
#pragma unroll
        for (int mt = 0; mt < 2; ++mt)
            paf[s][mt] = *(const bf16x8*)&P[(size_t)(b * LC + i0 + mt * 16 + l15) * LQ
                                           + s * 32 + quad * 8];

    const short* qTb = qT + ((size_t)b * DD + qd * 256 + w * 16 + l15) * LQ + quad * 8;

    for (int dci = 0; dci < 4; ++dci) {
        f32x4 acc2[2] = {{0.f,0.f,0.f,0.f},{0.f,0.f,0.f,0.f}};
#pragma unroll
        for (int s = 0; s < 2; ++s) {
            bf16x8 bf = *(const bf16x8*)(qTb + (size_t)dci * 64 * LQ + s * 32);
#pragma unroll
            for (int mt = 0; mt < 2; ++mt)
                acc2[mt] = __builtin_amdgcn_mfma_f32_16x16x32_bf16(paf[s][mt], bf, acc2[mt], 0, 0, 0);
        }

        float t0[4] = {acc2[0][0], acc2[0][1], acc2[0][2], acc2[0][3]};
        float t1[4] = {acc2[1][0], acc2[1][1], acc2[1][2], acc2[1][3]};
        xpose44(t0, l15);
        xpose44(t1, l15);

        const int dglob = qd * 256 + dci * 64 + w * 16 + 4 * (l15 >> 2);
        float4 g2 = *(const float4*)(q2c + b * DD + dglob);

#pragma unroll
        for (int mt = 0; mt < 2; ++mt) {
            const int row = i0 + mt * 16 + quad * 4 + (l15 & 3);
            float4 cqv = mt ? *(float4*)t1 : *(float4*)t0;
            float4 cc = *(const float4*)(c + (size_t)(b * LC + row) * DD + dglob);
            float* ob = out + (size_t)(b * LC + row) * (4 * DD) + dglob;
            *(float4*)(ob) = cc;
            *(float4*)(ob + DD) = cqv;
            float4 o2 = {cc.x * g2.x, cc.y * g2.y, cc.z * g2.z, cc.w * g2.w};
            *(float4*)(ob + 2 * DD) = o2;
            float4 o3 = {cc.x * cqv.x, cc.y * cqv.y, cc.z * cqv.z, cc.w * cqv.w};
            *(float4*)(ob + 3 * DD) = o3;
        }
    }
}

extern "C" void kernel_launch(void* const* d_in, const int* in_sizes, int n_in,
                              void* d_out, int out_size, void* d_ws, size_t ws_size,
                              hipStream_t stream) {
    const float* c       = (const float*)d_in[0];
    const float* q       = (const float*)d_in[1];
    const float* proj_c  = (const float*)d_in[2];
    const float* proj_q  = (const float*)d_in[3];
    const float* proj_cq = (const float*)d_in[4];
    float* out = (float*)d_out;
    float* ws  = (float*)d_ws;

    float* mfull  = ws;                        // [B*LC]
    float* s0g    = ws + 16384;                // [B*LC]
    float* q2c    = ws + 32768;                // [B*DD]
    float* s1part = ws + 65536;                // [B*16*64]
    short* P      = (short*)(ws + 98304);      // [B*LC*LQ] bf16
    short* qbf    = (short*)(ws + 622592);     // [B*LQ*DD] bf16
    short* qT     = (short*)(ws + 1671168);    // [B*DD*LQ] bf16
    short* Abf    = (short*)(ws + 2719744);    // [B*LC*DD] bf16

    hipLaunchKernelGGL(kprep, dim3(1024), dim3(256), 0, stream,
                       c, q, proj_c, proj_q, proj_cq, Abf, s0g, qbf, qT, s1part);
    hipLaunchKernelGGL(k1_sim, dim3(512),  dim3(256), 0, stream,
                       Abf, qbf, s0g, s1part, P, mfull);
    hipLaunchKernelGGL(k2_q2c, dim3(256),  dim3(256), 0, stream, c, mfull, q2c);
    hipLaunchKernelGGL(k3_out, dim3(2048), dim3(256), 0, stream, c, qT, P, q2c, out);
}

// Round 7
// 373.383 us; speedup vs baseline: 1.1171x; 1.1171x over previous
//
#include <hip/hip_runtime.h>

#define B 32
#define LC 512
#define LQ 64
#define DD 1024

// ws layout (floats):
// mfull  [B*LC]         @ 0        (16384)
// q2c    [B*DD]         @ 16384    (32768)   -> 49152
// s1part [B*16*64]      @ 49152    (32768)   -> 81920
// P      [B*LC*LQ] bf16 @ 81920    (524288)  -> 606208
// qbf    [B*LQ*DD] bf16 @ 606208   (1048576) -> 1654784
// qT     [B*DD*LQ] bf16 @ 1654784  (1048576) -> 2703360

typedef __attribute__((ext_vector_type(8))) short bf16x8;   // 8 bf16 (4 VGPRs)
typedef __attribute__((ext_vector_type(4))) float f32x4;    // MFMA C/D

__device__ inline short f2bf(float f) {
    unsigned u = __builtin_bit_cast(unsigned, f);
    u += 0x7FFFu + ((u >> 16) & 1u);   // RNE
    return (short)(u >> 16);
}

__device__ inline bf16x8 pack8(float4 a, float4 b) {
    bf16x8 r;
    r[0] = f2bf(a.x); r[1] = f2bf(a.y); r[2] = f2bf(a.z); r[3] = f2bf(a.w);
    r[4] = f2bf(b.x); r[5] = f2bf(b.y); r[6] = f2bf(b.z); r[7] = f2bf(b.w);
    return r;
}

__device__ inline float dot4(float4 a, float4 b) {
    return a.x * b.x + a.y * b.y + a.z * b.z + a.w * b.w;
}

// XCD-aware bijective swizzle (nwg % 8 == 0): each XCD gets a contiguous chunk.
__device__ inline int xswz(int bid, int nwg) {
    return (bid & 7) * (nwg >> 3) + (bid >> 3);
}

// ---------------- kernel 0: q -> bf16 (row-major qbf + transposed qT) + s1 partials ----------------
__global__ __launch_bounds__(256) void k0_q(const float* __restrict__ q,
                                            const float* __restrict__ proj_q,
                                            short* __restrict__ qbf,
                                            short* __restrict__ qT,
                                            float* __restrict__ s1part) {
    const int bid = xswz(blockIdx.x, 512);
    const int b  = bid >> 4;
    const int d0 = (bid & 15) * 64;
    const int sl = bid & 15;
    const int t  = threadIdx.x;

    __shared__ __align__(16) short tile[64][72];   // [local d][j]
    __shared__ float s1red[64][8];

    const int j0 = (t & 31) * 2;   // rows j0, j0+1
    const int dg = t >> 5;         // 0..7 -> d-offset dg*8

    const float* qr0 = q + (size_t)(b * LQ + j0) * DD + d0 + dg * 8;
    const float* qr1 = qr0 + DD;
    float4 x0 = *(const float4*)(qr0 + 0);
    float4 x1 = *(const float4*)(qr0 + 4);
    float4 y0 = *(const float4*)(qr1 + 0);
    float4 y1 = *(const float4*)(qr1 + 4);
    float4 p0 = *(const float4*)(proj_q + d0 + dg * 8);
    float4 p1 = *(const float4*)(proj_q + d0 + dg * 8 + 4);

    s1red[j0][dg]     = dot4(x0, p0) + dot4(x1, p1);
    s1red[j0 + 1][dg] = dot4(y0, p0) + dot4(y1, p1);

    *(bf16x8*)&qbf[(size_t)(b * LQ + j0) * DD + d0 + dg * 8]     = pack8(x0, x1);
    *(bf16x8*)&qbf[(size_t)(b * LQ + j0 + 1) * DD + d0 + dg * 8] = pack8(y0, y1);

    const float* fx0 = (const float*)&x0;
    const float* fx1 = (const float*)&x1;
    const float* fy0 = (const float*)&y0;
    const float* fy1 = (const float*)&y1;
#pragma unroll
    for (int e = 0; e < 8; ++e) {
        float v0 = (e < 4) ? fx0[e] : fx1[e - 4];
        float v1 = (e < 4) ? fy0[e] : fy1[e - 4];
        unsigned pk = (unsigned)(unsigned short)f2bf(v0)
                    | ((unsigned)(unsigned short)f2bf(v1) << 16);
        *(unsigned*)&tile[dg * 8 + e][j0] = pk;
    }
    __syncthreads();

    {
        const int d = t >> 2, part = t & 3;
        bf16x8 v0 = *(const bf16x8*)&tile[d][part * 16];
        bf16x8 v1 = *(const bf16x8*)&tile[d][part * 16 + 8];
        short* dst = qT + ((size_t)b * DD + d0 + d) * LQ + part * 16;
        *(bf16x8*)(dst)     = v0;
        *(bf16x8*)(dst + 8) = v1;
    }
    if (t < 64) {
        float s = 0.f;
#pragma unroll
        for (int k = 0; k < 8; ++k) s += s1red[t][k];
        s1part[(b * 16 + sl) * 64 + t] = s;
    }
}

// ---------------- kernel 1: sim tile via bf16 MFMA, fused s0 + row softmax (R1 version) ----------------
__global__ __launch_bounds__(256) void k1_sim(const float* __restrict__ c,
                                              const short* __restrict__ qbf,
                                              const float* __restrict__ proj_c,
                                              const float* __restrict__ proj_cq,
                                              const float* __restrict__ s1part,
                                              short* __restrict__ P,
                                              float* __restrict__ mfull) {
    const int bid = xswz(blockIdx.x, 512);
    const int b  = bid >> 4;
    const int i0 = (bid & 15) * 32;
    const int t  = threadIdx.x;
    const int w  = t >> 6, lane = t & 63;
    const int l15 = lane & 15, quad = lane >> 4;

    __shared__ __align__(16) short sA[32][72];   // [row i][k]
    __shared__ __align__(16) short sB[64][72];   // [row j][k]
    __shared__ float rmaxL[32][4];
    __shared__ float rsumL[32][4];
    __shared__ float s0red[32][8];
    __shared__ float s1L[64];

    const int arow = t >> 3, ag = t & 7;    // A stage: row, d-off ag*8 (8 floats/thread)
    const int brow = t >> 2, bg = t & 3;    // B stage: row, 16 bf16/thread

    const float* cbase = c + (size_t)(b * LC + i0 + arow) * DD + ag * 8;
    const short* qbase = qbf + (size_t)(b * LQ + brow) * DD + bg * 16;

    f32x4 acc[2] = {{0.f,0.f,0.f,0.f},{0.f,0.f,0.f,0.f}};
    float s0p = 0.f;

    // prefetch chunk 0
    float4 a0 = *(const float4*)(cbase + 0);
    float4 a1 = *(const float4*)(cbase + 4);
    bf16x8 u0 = *(const bf16x8*)(qbase + 0);
    bf16x8 u1 = *(const bf16x8*)(qbase + 8);

    for (int kc = 0; kc < 16; ++kc) {
        float4 na0, na1;
        bf16x8 nu0, nu1;
        if (kc < 15) {
            const float* cn = cbase + (kc + 1) * 64;
            const short* qn = qbase + (kc + 1) * 64;
            na0 = *(const float4*)(cn + 0);
            na1 = *(const float4*)(cn + 4);
            nu0 = *(const bf16x8*)(qn + 0);
            nu1 = *(const bf16x8*)(qn + 8);
        }
        // convert A + stage + s0 partial (proj vectors are L1-hot)
        {
            const float* pcq = proj_cq + kc * 64 + ag * 8;
            const float* pc  = proj_c  + kc * 64 + ag * 8;
            float4 p0 = *(const float4*)(pcq + 0);
            float4 p1 = *(const float4*)(pcq + 4);
            float4 c0 = *(const float4*)(pc + 0);
            float4 c1 = *(const float4*)(pc + 4);
            s0p += dot4(a0, c0) + dot4(a1, c1);
            float4 m0 = {a0.x * p0.x, a0.y * p0.y, a0.z * p0.z, a0.w * p0.w};
            float4 m1 = {a1.x * p1.x, a1.y * p1.y, a1.z * p1.z, a1.w * p1.w};
            *(bf16x8*)&sA[arow][ag * 8] = pack8(m0, m1);
            *(bf16x8*)&sB[brow][bg * 16 + 0] = u0;
            *(bf16x8*)&sB[brow][bg * 16 + 8] = u1;
        }
        __syncthreads();
#pragma unroll
        for (int s = 0; s < 2; ++s) {
            int ko = s * 32 + quad * 8;
            bf16x8 bf = *(const bf16x8*)&sB[w * 16 + l15][ko];
#pragma unroll
            for (int mt = 0; mt < 2; ++mt) {
                bf16x8 af = *(const bf16x8*)&sA[mt * 16 + l15][ko];
                acc[mt] = __builtin_amdgcn_mfma_f32_16x16x32_bf16(af, bf, acc[mt], 0, 0, 0);
            }
        }
        __syncthreads();
        if (kc < 15) { a0 = na0; a1 = na1; u0 = nu0; u1 = nu1; }
    }

    // ---- epilogue: s1 gather, row softmax, write P bf16 + mfull ----
    s0red[arow][ag] = s0p;
    if (t < 64) {
        float s = 0.f;
#pragma unroll
        for (int k = 0; k < 16; ++k) s += s1part[(b * 16 + k) * 64 + t];
        s1L[t] = s;
    }
    __syncthreads();

    const float s1j = s1L[w * 16 + l15];
    float v[2][4];
#pragma unroll
    for (int mt = 0; mt < 2; ++mt) {
#pragma unroll
        for (int r = 0; r < 4; ++r) {
            float vv = acc[mt][r] + s1j;
            v[mt][r] = vv;
            float rm = vv;
#pragma unroll
            for (int off = 1; off < 16; off <<= 1) rm = fmaxf(rm, __shfl_xor(rm, off, 16));
            if (l15 == 0) rmaxL[mt * 16 + quad * 4 + r][w] = rm;
        }
    }
    __syncthreads();
    float e[2][4];
#pragma unroll
    for (int mt = 0; mt < 2; ++mt) {
#pragma unroll
        for (int r = 0; r < 4; ++r) {
            int row = mt * 16 + quad * 4 + r;
            float m = fmaxf(fmaxf(rmaxL[row][0], rmaxL[row][1]),
                            fmaxf(rmaxL[row][2], rmaxL[row][3]));
            float ee = __expf(v[mt][r] - m);
            e[mt][r] = ee;
            float se = ee;
#pragma unroll
            for (int off = 1; off < 16; off <<= 1) se += __shfl_xor(se, off, 16);
            if (l15 == 0) rsumL[row][w] = se;
        }
    }
    __syncthreads();
#pragma unroll
    for (int mt = 0; mt < 2; ++mt) {
#pragma unroll
        for (int r = 0; r < 4; ++r) {
            int row = mt * 16 + quad * 4 + r;
            float s = rsumL[row][0] + rsumL[row][1] + rsumL[row][2] + rsumL[row][3];
            P[(size_t)(b * LC + i0 + row) * LQ + w * 16 + l15] = f2bf(e[mt][r] / s);
        }
    }
    if (t < 32) {
        float s0v = 0.f;
#pragma unroll
        for (int k = 0; k < 8; ++k) s0v += s0red[t][k];
        float mm = fmaxf(fmaxf(rmaxL[t][0], rmaxL[t][1]),
                         fmaxf(rmaxL[t][2], rmaxL[t][3]));
        mfull[b * LC + i0 + t] = mm + s0v;
    }
}

// ---------------- kernel 2: fused softmax_i(mfull) + q2c[b,d] = sum_i a[i]*c[b,i,d] ----------------
__global__ __launch_bounds__(256) void k2_q2c(const float* __restrict__ c,
                                              const float* __restrict__ mfull,
                                              float* __restrict__ q2c) {
    const int bid = xswz(blockIdx.x, 256);
    const int b  = bid >> 3;
    const int d0 = (bid & 7) * 128;
    const int t  = threadIdx.x;
    __shared__ float aL[LC];
    __shared__ float redm[4];
    __shared__ float reds[4];

    float m0 = mfull[b * LC + t];
    float m1 = mfull[b * LC + 256 + t];
    float mx = fmaxf(m0, m1);
#pragma unroll
    for (int off = 32; off; off >>= 1) mx = fmaxf(mx, __shfl_xor(mx, off, 64));
    if ((t & 63) == 0) redm[t >> 6] = mx;
    __syncthreads();
    float bm = fmaxf(fmaxf(redm[0], redm[1]), fmaxf(redm[2], redm[3]));
    float e0 = __expf(m0 - bm), e1 = __expf(m1 - bm);
    float s = e0 + e1;
#pragma unroll
    for (int off = 32; off; off >>= 1) s += __shfl_xor(s, off, 64);
    if ((t & 63) == 0) reds[t >> 6] = s;
    __syncthreads();
    float bs = reds[0] + reds[1] + reds[2] + reds[3];
    float inv = 1.0f / bs;
    aL[t] = e0 * inv;
    aL[t + 256] = e1 * inv;
    __syncthreads();

    const int tx = t & 31, ty = t >> 5;
    float4 acc = {0.f, 0.f, 0.f, 0.f};
    const float* cb = c + (size_t)b * LC * DD + d0 + tx * 4;
    for (int i = ty; i < LC; i += 8) {
        float a = aL[i];
        float4 cv = *(const float4*)(cb + (size_t)i * DD);
        acc.x += a * cv.x; acc.y += a * cv.y; acc.z += a * cv.z; acc.w += a * cv.w;
    }
    __shared__ __align__(16) float4 red[8][32];
    red[ty][tx] = acc;
    __syncthreads();
    if (t < 32) {
        float4 sv = red[0][t];
#pragma unroll
        for (int k = 1; k < 8; ++k) {
            float4 v2 = red[k][t];
            sv.x += v2.x; sv.y += v2.y; sv.z += v2.z; sv.w += v2.w;
        }
        *(float4*)(q2c + b * DD + d0 + t * 4) = sv;
    }
}

// ---------------- kernel 3: c2q + concat with CONTIGUOUS 1-KB wave stores ----------------
// 1024 blocks = (b, 16-row tile), 256 threads = 4 waves, 4 blocks/CU (16.6 KB LDS).
// Per 256-d group: 4 MFMA chunks accumulate into ct[16][260]; barrier; each wave
// writes whole row-segments: one store inst = 64 lanes x float4 = 1 KB contiguous.
__global__ __launch_bounds__(256) void k3_out(const float* __restrict__ c,
                                              const short* __restrict__ qT,
                                              const short* __restrict__ P,
                                              const float* __restrict__ q2c,
                                              float* __restrict__ out) {
    const int bid = xswz(blockIdx.x, 1024);
    const int b  = bid >> 5;
    const int i0 = (bid & 31) * 16;
    const int t  = threadIdx.x;
    const int w  = t >> 6, lane = t & 63;
    const int l15 = lane & 15, quad = lane >> 4;

    __shared__ __align__(16) float ct[16][260];   // [row][d in group], pad 260

    // P A-fragments (16 rows), reg-resident, invariant over d
    bf16x8 paf[2];
#pragma unroll
    for (int s = 0; s < 2; ++s)
        paf[s] = *(const bf16x8*)&P[(size_t)(b * LC + i0 + l15) * LQ + s * 32 + quad * 8];

    // B-frag base: lane d-col = w*16 + l15 within chunk; k = quad*8 + s*32
    const short* qTb = qT + ((size_t)b * DD + w * 16 + l15) * LQ + quad * 8;

    for (int g = 0; g < 4; ++g) {
#pragma unroll
        for (int dci = 0; dci < 4; ++dci) {
            const int dloc = g * 256 + dci * 64;
            f32x4 acc2 = {0.f, 0.f, 0.f, 0.f};
#pragma unroll
            for (int s = 0; s < 2; ++s) {
                bf16x8 bf = *(const bf16x8*)(qTb + (size_t)dloc * LQ + s * 32);
                acc2 = __builtin_amdgcn_mfma_f32_16x16x32_bf16(paf[s], bf, acc2, 0, 0, 0);
            }
#pragma unroll
            for (int r = 0; r < 4; ++r)
                ct[quad * 4 + r][dci * 64 + w * 16 + l15] = acc2[r];
        }
        __syncthreads();

        // epilogue: wave w owns rows w*4..w*4+3; lane covers d = g*256 + lane*4
        const int dg = g * 256 + lane * 4;
        float4 g2 = *(const float4*)(q2c + b * DD + dg);
#pragma unroll
        for (int k = 0; k < 4; ++k) {
            const int row = w * 4 + k;
            float4 cc  = *(const float4*)(c + (size_t)(b * LC + i0 + row) * DD + dg);
            float4 cqv = *(const float4*)&ct[row][lane * 4];
            float* ob = out + (size_t)(b * LC + i0 + row) * (4 * DD) + dg;
            *(float4*)(ob) = cc;
            *(float4*)(ob + DD) = cqv;
            float4 o2 = {cc.x * g2.x, cc.y * g2.y, cc.z * g2.z, cc.w * g2.w};
            *(float4*)(ob + 2 * DD) = o2;
            float4 o3 = {cc.x * cqv.x, cc.y * cqv.y, cc.z * cqv.z, cc.w * cqv.w};
            *(float4*)(ob + 3 * DD) = o3;
        }
        __syncthreads();
    }
}

extern "C" void kernel_launch(void* const* d_in, const int* in_sizes, int n_in,
                              void* d_out, int out_size, void* d_ws, size_t ws_size,
                              hipStream_t stream) {
    const float* c       = (const float*)d_in[0];
    const float* q       = (const float*)d_in[1];
    const float* proj_c  = (const float*)d_in[2];
    const float* proj_q  = (const float*)d_in[3];
    const float* proj_cq = (const float*)d_in[4];
    float* out = (float*)d_out;
    float* ws  = (float*)d_ws;

    float* mfull  = ws;                        // [B*LC]
    float* q2c    = ws + 16384;                // [B*DD]
    float* s1part = ws + 49152;                // [B*16*64]
    short* P      = (short*)(ws + 81920);      // [B*LC*LQ] bf16
    short* qbf    = (short*)(ws + 606208);     // [B*LQ*DD] bf16
    short* qT     = (short*)(ws + 1654784);    // [B*DD*LQ] bf16

    hipLaunchKernelGGL(k0_q,   dim3(512),  dim3(256), 0, stream, q, proj_q, qbf, qT, s1part);
    hipLaunchKernelGGL(k1_sim, dim3(512),  dim3(256), 0, stream,
                       c, qbf, proj_c, proj_cq, s1part, P, mfull);
    hipLaunchKernelGGL(k2_q2c, dim3(256),  dim3(256), 0, stream, c, mfull, q2c);
    hipLaunchKernelGGL(k3_out, dim3(1024), dim3(256), 0, stream, c, qT, P, q2c, out);
}